// Round 13
// baseline (73.386 us; speedup 1.0000x reference)
//
#include <hip/hip_runtime.h>

#define HID 64
#define NTOK 66          // VOCAB_SIZE + 2
#define SEQ 64
#define WIN0 55          // SEQ_LEN - 1 - MEMORY_SLOTS
#define NW 8
#define NP 4             // window pairs
#define ITERS 8          // iterations per block (rows/block = 512, grid = 1024)
#define ROWS_PER_ITER 64 // 4 waves x 16 rows
#define LDS_STRIDE 72    // (LDS fallback kernel only)

// ws layout (ushort units): T1 at 0, T2 at NTOK*HID, Tpair at 2*NTOK*HID
#define T1_OFF 0
#define T2_OFF (NTOK * HID)
#define TP_OFF (2 * NTOK * HID)
#define WS_NEED_BYTES ((size_t)(2 * NTOK * HID + NTOK * NTOK * HID) * 2)

typedef _Float16 half8 __attribute__((ext_vector_type(8)));
typedef unsigned short ushort8v __attribute__((ext_vector_type(8)));
typedef float float4v __attribute__((ext_vector_type(4)));

static __device__ __forceinline__ unsigned short f2h(float f) {
    _Float16 h = (_Float16)f;
    union { _Float16 h; unsigned short u; } v; v.h = h;
    return v.u;
}

// Kernel 1: T1[t][n] = b1[n] + sum_k emb[t][k]*W1[n][k]
//           T2[t][n] = 0.125 * sum_k emb[t][k]*W1[n][64+k]   (f16)
__global__ void build_tables(const float* __restrict__ embed,
                             const float* __restrict__ W1,
                             const float* __restrict__ b1,
                             unsigned short* __restrict__ tbl) {
    int b = blockIdx.x;      // 0..131
    int tb = b & 1;
    int t  = b >> 1;
    int n  = threadIdx.x;    // 0..63
    float acc = tb ? 0.0f : b1[n];
    const float* er = embed + t * HID;
    const float* wr = W1 + n * (2 * HID) + tb * HID;
#pragma unroll 8
    for (int k = 0; k < HID; ++k) acc += er[k] * wr[k];
    if (tb) acc *= 0.125f;
    tbl[tb * (NTOK * HID) + t * HID + n] = f2h(acc);
}

// Kernel 1b: Tpair[a*66+b][n] = T2[a][n] + T2[b][n]  (f16, 4356 x 64)
__global__ void build_pairs(const unsigned short* __restrict__ tbl,
                            unsigned short* __restrict__ ws) {
    int idx = blockIdx.x * 64 + threadIdx.x;  // (pair, 8-chunk): 4356*8 items
    int p = idx >> 3;
    int c = (idx & 7) << 3;
    if (p >= NTOK * NTOK) return;
    int a = p / NTOK;
    int b = p - a * NTOK;
    half8 va = *(const half8*)(tbl + T2_OFF + a * HID + c);
    half8 vb = *(const half8*)(tbl + T2_OFF + b * HID + c);
    half8 s = va + vb;
    *(half8*)(ws + TP_OFF + p * HID + c) = s;
}

// ---------------------------------------------------------------------------
// Kernel 2 (PAIRS): logits^T = W2 (A-op) x h^T (B-op), mfma_f32_16x16x32_f16.
// Gather from GLOBAL (L2/L3-resident 545KB pair table): per chunk 1 T1 row +
// 4 pair rows = 5 loads (vs 9 LDS reads). Zero LDS -> no fill, no barrier,
// no bank conflicts; gather rides the VMEM pipe under the HBM store stream.
// Ping-pong stage (gP=chunk0, gQ=chunk1) gives one full iteration of
// prefetch distance to hide L2/L3 latency. All stage indices static.
// ---------------------------------------------------------------------------
__global__ __launch_bounds__(256, 3) void fused_forward_gp(
    const int* __restrict__ seqs,
    const int* __restrict__ qtok,
    const float* __restrict__ W2,
    const float* __restrict__ b2,
    const unsigned short* __restrict__ ws,
    float* __restrict__ out)
{
    int tid  = threadIdx.x;
    int wv   = tid >> 6;
    int l    = tid & 63;
    int lrow = l & 15;          // W2 row within n-tile / batch row within tile
    int lg   = l >> 4;
    int lk8  = lg * 8;          // ushort offset within 32-wide K chunk

    int row0 = blockIdx.x * (ITERS * ROWS_PER_ITER) + wv * 16 + lrow;

    const unsigned short* t1p = ws + T1_OFF;
    const unsigned short* tpp = ws + TP_OFF;

    int qA, qB;
    int pA[NP], pB[NP];
    half8 gP[NP + 1], gQ[NP + 1];   // [0..3]=pair rows, [4]=T1 row
    half8 a0, a1;
    float4v acc4[4];

// tokens + pair indices (scalar loads: proven-clean HBM traffic)
#define LOADT(s, t_) { \
    int row_ = row0 + (t_) * ROWS_PER_ITER; \
    q##s = qtok[row_]; \
    const int* sp_ = seqs + row_ * SEQ + WIN0; \
    int w0_=sp_[0], w1_=sp_[1], w2_=sp_[2], w3_=sp_[3]; \
    int w4_=sp_[4], w5_=sp_[5], w6_=sp_[6], w7_=sp_[7]; \
    p##s[0] = w0_ * NTOK + w1_;  p##s[1] = w2_ * NTOK + w3_; \
    p##s[2] = w4_ * NTOK + w5_;  p##s[3] = w6_ * NTOK + w7_; \
}

// fill one stage buffer (prologue only)
#define GATHER(g, qq, pp, koff) { \
    (g)[NP] = *(const half8*)(t1p + (qq) * HID + (koff)); \
    _Pragma("unroll") \
    for (int j = 0; j < NP; ++j) \
        (g)[j] = *(const half8*)(tpp + (pp)[j] * HID + (koff)); \
}

// consume stage (sum+relu) while reissuing each slot for the NEXT iteration
#define SUM_REISSUE(aout, g, qq, pp, koff) { \
    half8 s_ = (g)[NP]; \
    (g)[NP] = *(const half8*)(t1p + (qq) * HID + (koff)); \
    _Pragma("unroll") \
    for (int j = 0; j < NP; ++j) { \
        s_ += (g)[j]; \
        (g)[j] = *(const half8*)(tpp + (pp)[j] * HID + (koff)); \
    } \
    half8 z_ = (half8)(_Float16)0; \
    aout = __builtin_elementwise_max(s_, z_); \
}

#define SUM_FINAL(aout, g) { \
    half8 s_ = (g)[NP]; \
    _Pragma("unroll") \
    for (int j = 0; j < NP; ++j) s_ += (g)[j]; \
    half8 z_ = (half8)(_Float16)0; \
    aout = __builtin_elementwise_max(s_, z_); \
}

#define MFMA_K0 { \
    _Pragma("unroll") \
    for (int nt = 0; nt < 4; ++nt) \
        acc4[nt] = __builtin_amdgcn_mfma_f32_16x16x32_f16(wfrag[nt][0], a0, b2v[nt], 0, 0, 0); \
}

#define MFMA_K1_ST(t_) { \
    float* op = out + (size_t)(row0 + (t_) * ROWS_PER_ITER) * HID; \
    _Pragma("unroll") \
    for (int nt = 0; nt < 4; ++nt) { \
        acc4[nt] = __builtin_amdgcn_mfma_f32_16x16x32_f16(wfrag[nt][1], a1, acc4[nt], 0, 0, 0); \
        *(float4v*)(op + nt * 16 + lg * 4) = acc4[nt]; \
    } \
}

// iter t: consume C's chunks (gP,gQ), reissue N's; prefetch C's tokens for t+2
#define ITER_MID(C, N, t_) { \
    SUM_REISSUE(a0, gP, q##N, p##N, lk8); \
    MFMA_K0; \
    SUM_REISSUE(a1, gQ, q##N, p##N, 32 + lk8); \
    MFMA_K1_ST(t_); \
    LOADT(C, (t_) + 2); \
}
#define ITER_NOLOAD(C, N, t_) { \
    SUM_REISSUE(a0, gP, q##N, p##N, lk8); \
    MFMA_K0; \
    SUM_REISSUE(a1, gQ, q##N, p##N, 32 + lk8); \
    MFMA_K1_ST(t_); \
}
#define ITER_LAST(C, t_) { \
    SUM_FINAL(a0, gP); \
    MFMA_K0; \
    SUM_FINAL(a1, gQ); \
    MFMA_K1_ST(t_); \
}

    // ---- (1) iter 0/1 tokens: HBM latency hides under W2 load + gather ----
    LOADT(A, 0);
    LOADT(B, 1);

    // ---- (2) W2 A-fragments in registers (whole 64x64, f16) + b2 float4 ----
    half8   wfrag[4][2];
    float4v b2v[4];
#pragma unroll
    for (int nt = 0; nt < 4; ++nt) {
        b2v[nt] = *(const float4v*)(b2 + nt * 16 + lg * 4);
#pragma unroll
        for (int kc = 0; kc < 2; ++kc) {
            const float* wp = W2 + (nt * 16 + lrow) * HID + kc * 32 + lk8;
            half8 f;
#pragma unroll
            for (int j = 0; j < 8; ++j) f[j] = (_Float16)wp[j];
            wfrag[nt][kc] = f;
        }
    }

    // ---- (3) prologue gather: iter0 both chunks ----
    GATHER(gP, qA, pA, lk8);
    GATHER(gQ, qA, pA, 32 + lk8);

    // ---- (4) 8 iterations, iter-depth ping-pong pipeline (all static) ----
    ITER_MID(A, B, 0);
    ITER_MID(B, A, 1);
    ITER_MID(A, B, 2);
    ITER_MID(B, A, 3);
    ITER_MID(A, B, 4);
    ITER_MID(B, A, 5);
    ITER_NOLOAD(A, B, 6);
    ITER_LAST(B, 7);

#undef LOADT
#undef GATHER
#undef SUM_REISSUE
#undef SUM_FINAL
#undef MFMA_K0
#undef MFMA_K1_ST
#undef ITER_MID
#undef ITER_NOLOAD
#undef ITER_LAST
}

// ---------------------------------------------------------------------------
// FALLBACK (ws too small for pair table): round-12 LDS kernel, verbatim.
// ---------------------------------------------------------------------------
__global__ __launch_bounds__(256, 3) void fused_forward_lds(
    const int* __restrict__ seqs,
    const int* __restrict__ qtok,
    const float* __restrict__ W2,
    const float* __restrict__ b2,
    const unsigned short* __restrict__ tbl,
    float* __restrict__ out)
{
    __shared__ unsigned short T_lds[2 * NTOK * LDS_STRIDE];

    int tid  = threadIdx.x;
    int wv   = tid >> 6;
    int l    = tid & 63;
    int lrow = l & 15;
    int lg   = l >> 4;
    int lk8  = lg * 8;

    int row0 = blockIdx.x * (ITERS * ROWS_PER_ITER) + wv * 16 + lrow;

    int qA, qB;
    int wA[NW], wB[NW];
    half8  g[9];
    half8  a0, a1;
    float4v acc4[4];

#define LOADT(s, t_) { \
    int row_ = row0 + (t_) * ROWS_PER_ITER; \
    q##s = qtok[row_]; \
    const int* sp_ = seqs + row_ * SEQ + WIN0; \
    _Pragma("unroll") \
    for (int j = 0; j < NW; ++j) w##s[j] = sp_[j]; \
}
#define GATHER_ALL(qq, ww, k0c) { \
    g[8] = *(const half8*)(T_lds + (qq) * LDS_STRIDE + (k0c)); \
    _Pragma("unroll") \
    for (int j = 0; j < NW; ++j) \
        g[j] = *(const half8*)(T_lds + NTOK * LDS_STRIDE + (ww)[j] * LDS_STRIDE + (k0c)); \
}
#define SUM_REISSUE(aout, qq, ww, k0c) { \
    half8 s_ = g[8]; \
    g[8] = *(const half8*)(T_lds + (qq) * LDS_STRIDE + (k0c)); \
    _Pragma("unroll") \
    for (int j = 0; j < NW; ++j) { \
        s_ += g[j]; \
        g[j] = *(const half8*)(T_lds + NTOK * LDS_STRIDE + (ww)[j] * LDS_STRIDE + (k0c)); \
    } \
    half8 z_ = (half8)(_Float16)0; \
    aout = __builtin_elementwise_max(s_, z_); \
}
#define SUM_FINAL(aout) { \
    half8 s_ = g[8]; \
    _Pragma("unroll") \
    for (int j = 0; j < NW; ++j) s_ += g[j]; \
    half8 z_ = (half8)(_Float16)0; \
    aout = __builtin_elementwise_max(s_, z_); \
}
#define MFMA_K0 { \
    _Pragma("unroll") \
    for (int nt = 0; nt < 4; ++nt) \
        acc4[nt] = __builtin_amdgcn_mfma_f32_16x16x32_f16(wfrag[nt][0], a0, b2v[nt], 0, 0, 0); \
}
#define MFMA_K1_ST(t_) { \
    float* op = out + (size_t)(row0 + (t_) * ROWS_PER_ITER) * HID; \
    _Pragma("unroll") \
    for (int nt = 0; nt < 4; ++nt) { \
        acc4[nt] = __builtin_amdgcn_mfma_f32_16x16x32_f16(wfrag[nt][1], a1, acc4[nt], 0, 0, 0); \
        *(float4v*)(op + nt * 16 + lg * 4) = acc4[nt]; \
    } \
}
#define ITER_MID(C, N, t_) { \
    SUM_REISSUE(a0, q##C, w##C, 32 + lk8); \
    MFMA_K0; \
    SUM_REISSUE(a1, q##N, w##N, lk8); \
    MFMA_K1_ST(t_); \
    LOADT(C, (t_) + 2); \
}
#define ITER_NOLOAD(C, N, t_) { \
    SUM_REISSUE(a0, q##C, w##C, 32 + lk8); \
    MFMA_K0; \
    SUM_REISSUE(a1, q##N, w##N, lk8); \
    MFMA_K1_ST(t_); \
}
#define ITER_LAST(C, t_) { \
    SUM_REISSUE(a0, q##C, w##C, 32 + lk8); \
    MFMA_K0; \
    SUM_FINAL(a1); \
    MFMA_K1_ST(t_); \
}

    LOADT(A, 0);
    LOADT(B, 1);

    half8   wfrag[4][2];
    float4v b2v[4];
#pragma unroll
    for (int nt = 0; nt < 4; ++nt) {
        b2v[nt] = *(const float4v*)(b2 + nt * 16 + lg * 4);
#pragma unroll
        for (int kc = 0; kc < 2; ++kc) {
            const float* wp = W2 + (nt * 16 + lrow) * HID + kc * 32 + lk8;
            half8 f;
#pragma unroll
            for (int j = 0; j < 8; ++j) f[j] = (_Float16)wp[j];
            wfrag[nt][kc] = f;
        }
    }

    for (int i = tid; i < 2 * NTOK * (HID / 8); i += 256) {
        int tbi = i / (NTOK * 8);
        int rem = i - tbi * (NTOK * 8);
        int t   = rem >> 3;
        int kq  = (rem & 7) << 3;
        *(ushort8v*)(T_lds + tbi * (NTOK * LDS_STRIDE) + t * LDS_STRIDE + kq) =
            *(const ushort8v*)(tbl + tbi * (NTOK * HID) + t * HID + kq);
    }
    __syncthreads();

    GATHER_ALL(qA, wA, lk8);

    ITER_MID(A, B, 0);
    ITER_MID(B, A, 1);
    ITER_MID(A, B, 2);
    ITER_MID(B, A, 3);
    ITER_MID(A, B, 4);
    ITER_MID(B, A, 5);
    ITER_NOLOAD(A, B, 6);
    ITER_LAST(B, 7);

#undef LOADT
#undef GATHER_ALL
#undef SUM_REISSUE
#undef SUM_FINAL
#undef MFMA_K0
#undef MFMA_K1_ST
#undef ITER_MID
#undef ITER_NOLOAD
#undef ITER_LAST
}

extern "C" void kernel_launch(void* const* d_in, const int* in_sizes, int n_in,
                              void* d_out, int out_size, void* d_ws, size_t ws_size,
                              hipStream_t stream) {
    const int*   seqs  = (const int*)d_in[0];
    const int*   qtok  = (const int*)d_in[1];
    const float* embed = (const float*)d_in[2];
    const float* W1    = (const float*)d_in[3];
    const float* b1    = (const float*)d_in[4];
    const float* W2    = (const float*)d_in[5];
    const float* b2    = (const float*)d_in[6];
    float* out = (float*)d_out;
    unsigned short* tbl = (unsigned short*)d_ws;

    int B = in_sizes[0] / SEQ;
    int grid = B / (ITERS * ROWS_PER_ITER);

    build_tables<<<NTOK * 2, HID, 0, stream>>>(embed, W1, b1, tbl);

    if (ws_size >= WS_NEED_BYTES) {
        int pgrid = (NTOK * NTOK * 8 + 63) / 64;
        build_pairs<<<pgrid, 64, 0, stream>>>(tbl, tbl);
        fused_forward_gp<<<grid, 256, 0, stream>>>(seqs, qtok, W2, b2, tbl, out);
    } else {
        fused_forward_lds<<<grid, 256, 0, stream>>>(seqs, qtok, W2, b2, tbl, out);
    }
}

// Round 14
// 49.796 us; speedup vs baseline: 1.4737x; 1.4737x over previous
//
#include <hip/hip_runtime.h>

#define HID 64
#define NTOK 66          // VOCAB_SIZE + 2
#define SEQ 64
#define WIN0 55          // SEQ_LEN - 1 - MEMORY_SLOTS
#define NW 8
#define LDS_STRIDE 72    // ushorts per table row (144B; token -> bank-quad uniform)
#define ITERS 8          // iterations per block (rows/block = 512, grid = 1024)
#define ROWS_PER_ITER 64 // 4 waves x 16 rows

typedef _Float16 half8 __attribute__((ext_vector_type(8)));
typedef unsigned short ushort8v __attribute__((ext_vector_type(8)));
typedef float float4v __attribute__((ext_vector_type(4)));

static __device__ __forceinline__ unsigned short f2h(float f) {
    _Float16 h = (_Float16)f;
    union { _Float16 h; unsigned short u; } v; v.h = h;
    return v.u;
}

// Kernel 1: tables T1[t][n] = b1[n] + sum_k emb[t][k]*W1[n][k]
//           T2[t][n] = 0.125 * sum_k emb[t][k]*W1[n][64+k]
// stored F16 in ws: [2][66][64]
__global__ void build_tables(const float* __restrict__ embed,
                             const float* __restrict__ W1,
                             const float* __restrict__ b1,
                             unsigned short* __restrict__ tbl) {
    int b = blockIdx.x;      // 0..131
    int tb = b & 1;
    int t  = b >> 1;
    int n  = threadIdx.x;    // 0..63
    float acc = tb ? 0.0f : b1[n];
    const float* er = embed + t * HID;
    const float* wr = W1 + n * (2 * HID) + tb * HID;
#pragma unroll 8
    for (int k = 0; k < HID; ++k) acc += er[k] * wr[k];
    if (tb) acc *= 0.125f;
    tbl[tb * (NTOK * HID) + t * HID + n] = f2h(acc);
}

// Kernel 2: logits^T = W2 (A-op) x h^T (B-op) via mfma_f32_16x16x32_f16.
// Round-12 rotating single-buffer gather pipeline, plus:
//  (a) per-wave s_sleep stagger AFTER the barrier -> de-sync the 4-wave
//      convoy so LDS phases of one wave overlap store/HBM phases of others;
//  (b) token loads issued BEFORE the iteration's stores (vmcnt FIFO order)
//      so token consumption can never queue behind store drain.
__global__ __launch_bounds__(256, 3) void fused_forward(
    const int* __restrict__ seqs,
    const int* __restrict__ qtok,
    const float* __restrict__ W2,
    const float* __restrict__ b2,
    const unsigned short* __restrict__ tbl,
    float* __restrict__ out)
{
    __shared__ unsigned short T_lds[2 * NTOK * LDS_STRIDE]; // 19008 B

    int tid  = threadIdx.x;
    int wv   = tid >> 6;
    int l    = tid & 63;
    int lrow = l & 15;          // W2 row within n-tile / batch row within tile
    int lg   = l >> 4;
    int lk8  = lg * 8;          // k offset within 32-wide K chunk

    int row0 = blockIdx.x * (ITERS * ROWS_PER_ITER) + wv * 16 + lrow;

    int qA, qB;
    int wA[NW], wB[NW];
    half8  g[9];                // rotating stage: [0..7]=T2 rows, [8]=T1 row
    half8  a0, a1;
    float4v acc4[4];

// scalar token loads (proven-clean HBM traffic)
#define LOADT(s, t_) { \
    int row_ = row0 + (t_) * ROWS_PER_ITER; \
    q##s = qtok[row_]; \
    const int* sp_ = seqs + row_ * SEQ + WIN0; \
    _Pragma("unroll") \
    for (int j = 0; j < NW; ++j) w##s[j] = sp_[j]; \
}

// fill the stage buffer for one chunk (prologue only)
#define GATHER_ALL(qq, ww, k0c) { \
    g[8] = *(const half8*)(T_lds + (qq) * LDS_STRIDE + (k0c)); \
    _Pragma("unroll") \
    for (int j = 0; j < NW; ++j) \
        g[j] = *(const half8*)(T_lds + NTOK * LDS_STRIDE + (ww)[j] * LDS_STRIDE + (k0c)); \
}

// consume stage (sum+relu) while REISSUING each slot for the next chunk
#define SUM_REISSUE(aout, qq, ww, k0c) { \
    half8 s_ = g[8]; \
    g[8] = *(const half8*)(T_lds + (qq) * LDS_STRIDE + (k0c)); \
    _Pragma("unroll") \
    for (int j = 0; j < NW; ++j) { \
        s_ += g[j]; \
        g[j] = *(const half8*)(T_lds + NTOK * LDS_STRIDE + (ww)[j] * LDS_STRIDE + (k0c)); \
    } \
    half8 z_ = (half8)(_Float16)0; \
    aout = __builtin_elementwise_max(s_, z_); \
}

// final consume, no reissue
#define SUM_FINAL(aout) { \
    half8 s_ = g[8]; \
    _Pragma("unroll") \
    for (int j = 0; j < NW; ++j) s_ += g[j]; \
    half8 z_ = (half8)(_Float16)0; \
    aout = __builtin_elementwise_max(s_, z_); \
}

// first K-half of the MFMAs (C init = bias); runs under chunk1 read latency
#define MFMA_K0 { \
    _Pragma("unroll") \
    for (int nt = 0; nt < 4; ++nt) \
        acc4[nt] = __builtin_amdgcn_mfma_f32_16x16x32_f16(wfrag[nt][0], a0, b2v[nt], 0, 0, 0); \
}

// second K-half + stores; runs under next-iter chunk0 read latency
#define MFMA_K1_ST(t_) { \
    float* op = out + (size_t)(row0 + (t_) * ROWS_PER_ITER) * HID; \
    _Pragma("unroll") \
    for (int nt = 0; nt < 4; ++nt) { \
        acc4[nt] = __builtin_amdgcn_mfma_f32_16x16x32_f16(wfrag[nt][1], a1, acc4[nt], 0, 0, 0); \
        *(float4v*)(op + nt * 16 + lg * 4) = acc4[nt]; \
    } \
}

// iteration: consume C-chunk0 (reissue C-chunk1), TOKEN LOADS for t+2 (ahead
// of this iter's stores in the vmcnt FIFO), MFMA kc0, consume C-chunk1
// (reissue N-chunk0), MFMA kc1 + stores.
#define ITER_MID(C, N, t_) { \
    SUM_REISSUE(a0, q##C, w##C, 32 + lk8); \
    LOADT(C, (t_) + 2); \
    MFMA_K0; \
    SUM_REISSUE(a1, q##N, w##N, lk8); \
    MFMA_K1_ST(t_); \
}
#define ITER_NOLOAD(C, N, t_) { \
    SUM_REISSUE(a0, q##C, w##C, 32 + lk8); \
    MFMA_K0; \
    SUM_REISSUE(a1, q##N, w##N, lk8); \
    MFMA_K1_ST(t_); \
}
#define ITER_LAST(C, t_) { \
    SUM_REISSUE(a0, q##C, w##C, 32 + lk8); \
    MFMA_K0; \
    SUM_FINAL(a1); \
    MFMA_K1_ST(t_); \
}

    // ---- (1) iter 0/1 token loads: HBM latency hides under W2+fill+barrier ----
    LOADT(A, 0);
    LOADT(B, 1);

    // ---- (2) W2 A-fragments in registers (whole 64x64, f16) + b2 float4 ----
    half8   wfrag[4][2];
    float4v b2v[4];
#pragma unroll
    for (int nt = 0; nt < 4; ++nt) {
        b2v[nt] = *(const float4v*)(b2 + nt * 16 + lg * 4);
#pragma unroll
        for (int kc = 0; kc < 2; ++kc) {
            const float* wp = W2 + (nt * 16 + lrow) * HID + kc * 32 + lk8;
            half8 f;
#pragma unroll
            for (int j = 0; j < 8; ++j) f[j] = (_Float16)wp[j];
            wfrag[nt][kc] = f;
        }
    }

    // ---- (3) fill LDS tables (16B chunks; row stride 144B) ----
    for (int i = tid; i < 2 * NTOK * (HID / 8); i += 256) {
        int tbi = i / (NTOK * 8);
        int rem = i - tbi * (NTOK * 8);
        int t   = rem >> 3;
        int kq  = (rem & 7) << 3;
        *(ushort8v*)(T_lds + tbi * (NTOK * LDS_STRIDE) + t * LDS_STRIDE + kq) =
            *(const ushort8v*)(tbl + tbi * (NTOK * HID) + t * HID + kq);
    }
    __syncthreads();

    // ---- (3b) convoy de-sync: stagger waves 0/512/1024/1536 cycles.
    // s_sleep takes an immediate, so use wave-uniform scalar branches.
    if (wv & 1) { __builtin_amdgcn_s_sleep(8); }
    if (wv & 2) { __builtin_amdgcn_s_sleep(8); __builtin_amdgcn_s_sleep(8); }

    // ---- (4) rotating-buffer pipeline over 8 iterations (all static) ----
    GATHER_ALL(qA, wA, lk8);    // prologue: iter0 chunk0

    ITER_MID(A, B, 0);
    ITER_MID(B, A, 1);
    ITER_MID(A, B, 2);
    ITER_MID(B, A, 3);
    ITER_MID(A, B, 4);
    ITER_MID(B, A, 5);
    ITER_NOLOAD(A, B, 6);
    ITER_LAST(B, 7);

#undef LOADT
#undef GATHER_ALL
#undef SUM_REISSUE
#undef SUM_FINAL
#undef MFMA_K0
#undef MFMA_K1_ST
#undef ITER_MID
#undef ITER_NOLOAD
#undef ITER_LAST
}

extern "C" void kernel_launch(void* const* d_in, const int* in_sizes, int n_in,
                              void* d_out, int out_size, void* d_ws, size_t ws_size,
                              hipStream_t stream) {
    const int*   seqs  = (const int*)d_in[0];
    const int*   qtok  = (const int*)d_in[1];
    const float* embed = (const float*)d_in[2];
    const float* W1    = (const float*)d_in[3];
    const float* b1    = (const float*)d_in[4];
    const float* W2    = (const float*)d_in[5];
    const float* b2    = (const float*)d_in[6];
    float* out = (float*)d_out;
    unsigned short* tbl = (unsigned short*)d_ws;

    int B = in_sizes[0] / SEQ;

    build_tables<<<NTOK * 2, HID, 0, stream>>>(embed, W1, b1, tbl);

    int grid = B / (ITERS * ROWS_PER_ITER);
    fused_forward<<<grid, 256, 0, stream>>>(seqs, qtok, W2, b2, tbl, out);
}

// Round 15
// 48.393 us; speedup vs baseline: 1.5165x; 1.0290x over previous
//
#include <hip/hip_runtime.h>

#define HID 64
#define NTOK 66          // VOCAB_SIZE + 2
#define SEQ 64
#define WIN0 55          // SEQ_LEN - 1 - MEMORY_SLOTS
#define NW 8
#define LDS_STRIDE 72    // ushorts per table row (144B; token -> bank-quad uniform)
#define ITERS 8          // iterations per block (rows/block = 1024, grid = 512)
#define BLOCK 512        // 8 waves
#define ROWS_PER_ITER 128 // 8 waves x 16 rows

typedef _Float16 half8 __attribute__((ext_vector_type(8)));
typedef unsigned short ushort8v __attribute__((ext_vector_type(8)));
typedef float float4v __attribute__((ext_vector_type(4)));

static __device__ __forceinline__ unsigned short f2h(float f) {
    _Float16 h = (_Float16)f;
    union { _Float16 h; unsigned short u; } v; v.h = h;
    return v.u;
}

// Kernel 1: tables T1[t][n] = b1[n] + sum_k emb[t][k]*W1[n][k]
//           T2[t][n] = 0.125 * sum_k emb[t][k]*W1[n][64+k]
// stored F16 in ws: [2][66][64]
__global__ void build_tables(const float* __restrict__ embed,
                             const float* __restrict__ W1,
                             const float* __restrict__ b1,
                             unsigned short* __restrict__ tbl) {
    int b = blockIdx.x;      // 0..131
    int tb = b & 1;
    int t  = b >> 1;
    int n  = threadIdx.x;    // 0..63
    float acc = tb ? 0.0f : b1[n];
    const float* er = embed + t * HID;
    const float* wr = W1 + n * (2 * HID) + tb * HID;
#pragma unroll 8
    for (int k = 0; k < HID; ++k) acc += er[k] * wr[k];
    if (tb) acc *= 0.125f;
    tbl[tb * (NTOK * HID) + t * HID + n] = f2h(acc);
}

// Kernel 2: logits^T = W2 (A-op) x h^T (B-op) via mfma_f32_16x16x32_f16.
// R12 rotating single-buffer gather pipeline, with 512-thread blocks:
// grid 512 = 2 blocks/CU x 8 waves = 16 resident waves/CU (vs ~8 at
// grid 1024/256-thread blocks) -> cross-wave overlap of LDS phases with
// HBM store drain; prologue (fill + W2 frags) paid half as often.
__global__ __launch_bounds__(BLOCK, 3) void fused_forward(
    const int* __restrict__ seqs,
    const int* __restrict__ qtok,
    const float* __restrict__ W2,
    const float* __restrict__ b2,
    const unsigned short* __restrict__ tbl,
    float* __restrict__ out)
{
    __shared__ unsigned short T_lds[2 * NTOK * LDS_STRIDE]; // 19008 B

    int tid  = threadIdx.x;
    int wv   = tid >> 6;        // 0..7
    int l    = tid & 63;
    int lrow = l & 15;          // W2 row within n-tile / batch row within tile
    int lg   = l >> 4;
    int lk8  = lg * 8;          // k offset within 32-wide K chunk

    int row0 = blockIdx.x * (ITERS * ROWS_PER_ITER) + wv * 16 + lrow;

    int qA, qB;
    int wA[NW], wB[NW];
    half8  g[9];                // rotating stage: [0..7]=T2 rows, [8]=T1 row
    half8  a0, a1;
    float4v acc4[4];

// scalar token loads (proven-clean HBM traffic)
#define LOADT(s, t_) { \
    int row_ = row0 + (t_) * ROWS_PER_ITER; \
    q##s = qtok[row_]; \
    const int* sp_ = seqs + row_ * SEQ + WIN0; \
    _Pragma("unroll") \
    for (int j = 0; j < NW; ++j) w##s[j] = sp_[j]; \
}

// fill the stage buffer for one chunk (prologue only)
#define GATHER_ALL(qq, ww, k0c) { \
    g[8] = *(const half8*)(T_lds + (qq) * LDS_STRIDE + (k0c)); \
    _Pragma("unroll") \
    for (int j = 0; j < NW; ++j) \
        g[j] = *(const half8*)(T_lds + NTOK * LDS_STRIDE + (ww)[j] * LDS_STRIDE + (k0c)); \
}

// consume stage (sum+relu) while REISSUING each slot for the next chunk
#define SUM_REISSUE(aout, qq, ww, k0c) { \
    half8 s_ = g[8]; \
    g[8] = *(const half8*)(T_lds + (qq) * LDS_STRIDE + (k0c)); \
    _Pragma("unroll") \
    for (int j = 0; j < NW; ++j) { \
        s_ += g[j]; \
        g[j] = *(const half8*)(T_lds + NTOK * LDS_STRIDE + (ww)[j] * LDS_STRIDE + (k0c)); \
    } \
    half8 z_ = (half8)(_Float16)0; \
    aout = __builtin_elementwise_max(s_, z_); \
}

// final consume, no reissue
#define SUM_FINAL(aout) { \
    half8 s_ = g[8]; \
    _Pragma("unroll") \
    for (int j = 0; j < NW; ++j) s_ += g[j]; \
    half8 z_ = (half8)(_Float16)0; \
    aout = __builtin_elementwise_max(s_, z_); \
}

// first K-half of the MFMAs (C init = bias); runs under chunk1 read latency
#define MFMA_K0 { \
    _Pragma("unroll") \
    for (int nt = 0; nt < 4; ++nt) \
        acc4[nt] = __builtin_amdgcn_mfma_f32_16x16x32_f16(wfrag[nt][0], a0, b2v[nt], 0, 0, 0); \
}

// second K-half + stores; runs under next-iter chunk0 read latency
#define MFMA_K1_ST(t_) { \
    float* op = out + (size_t)(row0 + (t_) * ROWS_PER_ITER) * HID; \
    _Pragma("unroll") \
    for (int nt = 0; nt < 4; ++nt) { \
        acc4[nt] = __builtin_amdgcn_mfma_f32_16x16x32_f16(wfrag[nt][1], a1, acc4[nt], 0, 0, 0); \
        *(float4v*)(op + nt * 16 + lg * 4) = acc4[nt]; \
    } \
}

// one pipelined iteration (R12 ordering, proven best)
#define ITER_MID(C, N, t_) { \
    SUM_REISSUE(a0, q##C, w##C, 32 + lk8); \
    MFMA_K0; \
    SUM_REISSUE(a1, q##N, w##N, lk8); \
    MFMA_K1_ST(t_); \
    LOADT(C, (t_) + 2); \
}
#define ITER_NOLOAD(C, N, t_) { \
    SUM_REISSUE(a0, q##C, w##C, 32 + lk8); \
    MFMA_K0; \
    SUM_REISSUE(a1, q##N, w##N, lk8); \
    MFMA_K1_ST(t_); \
}
#define ITER_LAST(C, t_) { \
    SUM_REISSUE(a0, q##C, w##C, 32 + lk8); \
    MFMA_K0; \
    SUM_FINAL(a1); \
    MFMA_K1_ST(t_); \
}

    // ---- (1) iter 0/1 token loads: HBM latency hides under W2+fill+barrier ----
    LOADT(A, 0);
    LOADT(B, 1);

    // ---- (2) W2 A-fragments in registers (whole 64x64, f16) + b2 float4 ----
    half8   wfrag[4][2];
    float4v b2v[4];
#pragma unroll
    for (int nt = 0; nt < 4; ++nt) {
        b2v[nt] = *(const float4v*)(b2 + nt * 16 + lg * 4);
#pragma unroll
        for (int kc = 0; kc < 2; ++kc) {
            const float* wp = W2 + (nt * 16 + lrow) * HID + kc * 32 + lk8;
            half8 f;
#pragma unroll
            for (int j = 0; j < 8; ++j) f[j] = (_Float16)wp[j];
            wfrag[nt][kc] = f;
        }
    }

    // ---- (3) fill LDS tables (16B chunks; row stride 144B) ----
    for (int i = tid; i < 2 * NTOK * (HID / 8); i += BLOCK) {
        int tbi = i / (NTOK * 8);
        int rem = i - tbi * (NTOK * 8);
        int t   = rem >> 3;
        int kq  = (rem & 7) << 3;
        *(ushort8v*)(T_lds + tbi * (NTOK * LDS_STRIDE) + t * LDS_STRIDE + kq) =
            *(const ushort8v*)(tbl + tbi * (NTOK * HID) + t * HID + kq);
    }
    __syncthreads();

    // ---- (4) rotating-buffer pipeline over 8 iterations (all static) ----
    GATHER_ALL(qA, wA, lk8);    // prologue: iter0 chunk0

    ITER_MID(A, B, 0);
    ITER_MID(B, A, 1);
    ITER_MID(A, B, 2);
    ITER_MID(B, A, 3);
    ITER_MID(A, B, 4);
    ITER_MID(B, A, 5);
    ITER_NOLOAD(A, B, 6);
    ITER_LAST(B, 7);

#undef LOADT
#undef GATHER_ALL
#undef SUM_REISSUE
#undef SUM_FINAL
#undef MFMA_K0
#undef MFMA_K1_ST
#undef ITER_MID
#undef ITER_NOLOAD
#undef ITER_LAST
}

extern "C" void kernel_launch(void* const* d_in, const int* in_sizes, int n_in,
                              void* d_out, int out_size, void* d_ws, size_t ws_size,
                              hipStream_t stream) {
    const int*   seqs  = (const int*)d_in[0];
    const int*   qtok  = (const int*)d_in[1];
    const float* embed = (const float*)d_in[2];
    const float* W1    = (const float*)d_in[3];
    const float* b1    = (const float*)d_in[4];
    const float* W2    = (const float*)d_in[5];
    const float* b2    = (const float*)d_in[6];
    float* out = (float*)d_out;
    unsigned short* tbl = (unsigned short*)d_ws;

    int B = in_sizes[0] / SEQ;

    build_tables<<<NTOK * 2, HID, 0, stream>>>(embed, W1, b1, tbl);

    int grid = B / (ITERS * ROWS_PER_ITER);
    fused_forward<<<grid, BLOCK, 0, stream>>>(seqs, qtok, W2, b2, tbl, out);
}

// Round 16
// 47.528 us; speedup vs baseline: 1.5440x; 1.0182x over previous
//
#include <hip/hip_runtime.h>

#define HID 64
#define NTOK 66          // VOCAB_SIZE + 2
#define SEQ 64
#define WIN0 55          // SEQ_LEN - 1 - MEMORY_SLOTS
#define NW 8
#define LDS_STRIDE 72    // ushorts per table row (144B; bank-residue floor is geometric)
#define ITERS 8          // iterations per block (rows/block = 1024, grid = 512)
#define BLOCK 512        // 8 waves
#define ROWS_PER_ITER 128 // 8 waves x 16 rows

typedef _Float16 half8 __attribute__((ext_vector_type(8)));
typedef unsigned short ushort8v __attribute__((ext_vector_type(8)));
typedef float float4v __attribute__((ext_vector_type(4)));

static __device__ __forceinline__ unsigned short f2h(float f) {
    _Float16 h = (_Float16)f;
    union { _Float16 h; unsigned short u; } v; v.h = h;
    return v.u;
}

// Kernel 1: tables T1[t][n] = b1[n] + sum_k emb[t][k]*W1[n][k]
//           T2[t][n] = 0.125 * sum_k emb[t][k]*W1[n][64+k]
// stored F16 in ws: [2][66][64]
__global__ void build_tables(const float* __restrict__ embed,
                             const float* __restrict__ W1,
                             const float* __restrict__ b1,
                             unsigned short* __restrict__ tbl) {
    int b = blockIdx.x;      // 0..131
    int tb = b & 1;
    int t  = b >> 1;
    int n  = threadIdx.x;    // 0..63
    float acc = tb ? 0.0f : b1[n];
    const float* er = embed + t * HID;
    const float* wr = W1 + n * (2 * HID) + tb * HID;
#pragma unroll 8
    for (int k = 0; k < HID; ++k) acc += er[k] * wr[k];
    if (tb) acc *= 0.125f;
    tbl[tb * (NTOK * HID) + t * HID + n] = f2h(acc);
}

// Kernel 2: logits^T = W2 (A-op) x h^T (B-op) via mfma_f32_16x16x32_f16.
// DEPTH-2 rotating gather pipeline: TWO stage buffers (g0 = chunk0 of iter
// t, g1 = chunk1 of iter t). Each consume reissues the slot with iter
// t+1's indices -> every LDS read has a FULL-ITERATION shadow (vs 1/4
// iteration in R12/R15). Register cost +36 VGPR; launch_bounds(512,2)
// gives a 256-reg budget (no spill possible at ~180), and measured
// residency has been ~2 waves/SIMD for all fast variants anyway
// (occupancy negatively correlated with speed across R5/R12/R15).
__global__ __launch_bounds__(BLOCK, 2) void fused_forward(
    const int* __restrict__ seqs,
    const int* __restrict__ qtok,
    const float* __restrict__ W2,
    const float* __restrict__ b2,
    const unsigned short* __restrict__ tbl,
    float* __restrict__ out)
{
    __shared__ unsigned short T_lds[2 * NTOK * LDS_STRIDE]; // 19008 B

    int tid  = threadIdx.x;
    int wv   = tid >> 6;        // 0..7
    int l    = tid & 63;
    int lrow = l & 15;          // W2 row within n-tile / batch row within tile
    int lg   = l >> 4;
    int lk8  = lg * 8;          // k offset within 32-wide K chunk

    int row0 = blockIdx.x * (ITERS * ROWS_PER_ITER) + wv * 16 + lrow;

    int qA, qB;
    int wA[NW], wB[NW];
    half8  g0[9], g1[9];        // stage buffers: chunk0 / chunk1 of current iter
    half8  a0, a1;
    float4v acc4[4];

// scalar token loads (proven-clean HBM traffic)
#define LOADT(s, t_) { \
    int row_ = row0 + (t_) * ROWS_PER_ITER; \
    q##s = qtok[row_]; \
    const int* sp_ = seqs + row_ * SEQ + WIN0; \
    _Pragma("unroll") \
    for (int j = 0; j < NW; ++j) w##s[j] = sp_[j]; \
}

// fill one stage buffer (prologue only)
#define GATHER_ALL(g, qq, ww, k0c) { \
    (g)[8] = *(const half8*)(T_lds + (qq) * LDS_STRIDE + (k0c)); \
    _Pragma("unroll") \
    for (int j = 0; j < NW; ++j) \
        (g)[j] = *(const half8*)(T_lds + NTOK * LDS_STRIDE + (ww)[j] * LDS_STRIDE + (k0c)); \
}

// consume stage (sum+relu) while REISSUING each slot with NEXT ITER's tokens
#define SUM_REISSUE(aout, g, qq, ww, k0c) { \
    half8 s_ = (g)[8]; \
    (g)[8] = *(const half8*)(T_lds + (qq) * LDS_STRIDE + (k0c)); \
    _Pragma("unroll") \
    for (int j = 0; j < NW; ++j) { \
        s_ += (g)[j]; \
        (g)[j] = *(const half8*)(T_lds + NTOK * LDS_STRIDE + (ww)[j] * LDS_STRIDE + (k0c)); \
    } \
    half8 z_ = (half8)(_Float16)0; \
    aout = __builtin_elementwise_max(s_, z_); \
}

// final consume, no reissue
#define SUM_FINAL(aout, g) { \
    half8 s_ = (g)[8]; \
    _Pragma("unroll") \
    for (int j = 0; j < NW; ++j) s_ += (g)[j]; \
    half8 z_ = (half8)(_Float16)0; \
    aout = __builtin_elementwise_max(s_, z_); \
}

// first K-half of the MFMAs (C init = bias)
#define MFMA_K0 { \
    _Pragma("unroll") \
    for (int nt = 0; nt < 4; ++nt) \
        acc4[nt] = __builtin_amdgcn_mfma_f32_16x16x32_f16(wfrag[nt][0], a0, b2v[nt], 0, 0, 0); \
}

// second K-half + stores
#define MFMA_K1_ST(t_) { \
    float* op = out + (size_t)(row0 + (t_) * ROWS_PER_ITER) * HID; \
    _Pragma("unroll") \
    for (int nt = 0; nt < 4; ++nt) { \
        acc4[nt] = __builtin_amdgcn_mfma_f32_16x16x32_f16(wfrag[nt][1], a1, acc4[nt], 0, 0, 0); \
        *(float4v*)(op + nt * 16 + lg * 4) = acc4[nt]; \
    } \
}

// iter t (tokens C current... consumed stages were filled with C's indices
// at iter t-1): consume g0/g1, reissue with N's (= t+1) indices; prefetch
// tokens for t+3 into C's slots (C is dead after the reissues).
#define ITER_MID(C, N, t_) { \
    SUM_REISSUE(a0, g0, q##N, w##N, lk8); \
    MFMA_K0; \
    SUM_REISSUE(a1, g1, q##N, w##N, 32 + lk8); \
    MFMA_K1_ST(t_); \
    LOADT(C, (t_) + 2); \
}
#define ITER_NOLOAD(C, N, t_) { \
    SUM_REISSUE(a0, g0, q##N, w##N, lk8); \
    MFMA_K0; \
    SUM_REISSUE(a1, g1, q##N, w##N, 32 + lk8); \
    MFMA_K1_ST(t_); \
}
#define ITER_LAST(t_) { \
    SUM_FINAL(a0, g0); \
    MFMA_K0; \
    SUM_FINAL(a1, g1); \
    MFMA_K1_ST(t_); \
}

    // ---- (1) iter 0/1 token loads: HBM latency hides under W2+fill+barrier ----
    LOADT(A, 0);
    LOADT(B, 1);

    // ---- (2) W2 A-fragments in registers (whole 64x64, f16) + b2 float4 ----
    half8   wfrag[4][2];
    float4v b2v[4];
#pragma unroll
    for (int nt = 0; nt < 4; ++nt) {
        b2v[nt] = *(const float4v*)(b2 + nt * 16 + lg * 4);
#pragma unroll
        for (int kc = 0; kc < 2; ++kc) {
            const float* wp = W2 + (nt * 16 + lrow) * HID + kc * 32 + lk8;
            half8 f;
#pragma unroll
            for (int j = 0; j < 8; ++j) f[j] = (_Float16)wp[j];
            wfrag[nt][kc] = f;
        }
    }

    // ---- (3) fill LDS tables (16B chunks; row stride 144B) ----
    for (int i = tid; i < 2 * NTOK * (HID / 8); i += BLOCK) {
        int tbi = i / (NTOK * 8);
        int rem = i - tbi * (NTOK * 8);
        int t   = rem >> 3;
        int kq  = (rem & 7) << 3;
        *(ushort8v*)(T_lds + tbi * (NTOK * LDS_STRIDE) + t * LDS_STRIDE + kq) =
            *(const ushort8v*)(tbl + tbi * (NTOK * HID) + t * HID + kq);
    }
    __syncthreads();

    // ---- (4) depth-2 pipeline over 8 iterations (all indices static) ----
    GATHER_ALL(g0, qA, wA, lk8);        // iter0 chunk0
    GATHER_ALL(g1, qA, wA, 32 + lk8);   // iter0 chunk1

    // iter t consumes stages pre-filled with iter-t tokens and reissues with
    // iter-t+1 tokens; token regs for t+2 loaded mid-iteration.
    ITER_MID(A, B, 0);      // consume A(0), reissue B(1), load A<-2
    ITER_MID(B, A, 1);      // consume B(1), reissue A(2), load B<-3
    ITER_MID(A, B, 2);
    ITER_MID(B, A, 3);
    ITER_MID(A, B, 4);
    ITER_MID(B, A, 5);
    ITER_NOLOAD(A, B, 6);   // consume A(6), reissue B(7)
    ITER_LAST(7);           // consume B(7)

#undef LOADT
#undef GATHER_ALL
#undef SUM_REISSUE
#undef SUM_FINAL
#undef MFMA_K0
#undef MFMA_K1_ST
#undef ITER_MID
#undef ITER_NOLOAD
#undef ITER_LAST
}

extern "C" void kernel_launch(void* const* d_in, const int* in_sizes, int n_in,
                              void* d_out, int out_size, void* d_ws, size_t ws_size,
                              hipStream_t stream) {
    const int*   seqs  = (const int*)d_in[0];
    const int*   qtok  = (const int*)d_in[1];
    const float* embed = (const float*)d_in[2];
    const float* W1    = (const float*)d_in[3];
    const float* b1    = (const float*)d_in[4];
    const float* W2    = (const float*)d_in[5];
    const float* b2    = (const float*)d_in[6];
    float* out = (float*)d_out;
    unsigned short* tbl = (unsigned short*)d_ws;

    int B = in_sizes[0] / SEQ;

    build_tables<<<NTOK * 2, HID, 0, stream>>>(embed, W1, b1, tbl);

    int grid = B / (ITERS * ROWS_PER_ITER);
    fused_forward<<<grid, BLOCK, 0, stream>>>(seqs, qtok, W2, b2, tbl, out);
}